// Round 1
// baseline (65641.974 us; speedup 1.0000x reference)
//
#include <hip/hip_runtime.h>
#include <hip/hip_bf16.h>

// LSTM: V=50000, E=512, H=512, S=16384, batch=1.
// Phase 1: gx[t][c] = emb[x[t]] . W_ih[c] + (b_ih[c]+b_hh[c])  (fp32 GEMM, bf16 store, permuted cols)
// Phase 2: persistent 32-wg kernel, spin-barrier per timestep, W_hh slice in VGPRs.
// Phase 3 (inside phase 2, wg 0): sigmoid(h W1^T+b1) -> sigmoid(. W2^T+b2) -> out[9].

#define S_LEN 16384
#define HID   512
#define NWG   32
#define HW    16      // hidden units per wg

static __device__ __forceinline__ float bf2f(unsigned short u) {
  union { unsigned int i; float f; } v; v.i = ((unsigned int)u) << 16; return v.f;
}
static __device__ __forceinline__ unsigned short f2bf(float f) {
  union { float f; unsigned int i; } v; v.f = f;
  unsigned int r = v.i + 0x7fffu + ((v.i >> 16) & 1u);
  return (unsigned short)(r >> 16);
}
static __device__ __forceinline__ float fsig(float x) { return 1.f / (1.f + __expf(-x)); }
static __device__ __forceinline__ float ftanh(float x) { return 2.f / (1.f + __expf(-2.f * x)) - 1.f; }

// ---------------- Phase 1: gx GEMM ----------------
// C[t][c] over t-tile 64 x c-tile 64, K=512 in chunks of 32. fp32 VALU.
// Store permuted: c -> [w = (c&511)>>4][r = (c>>9)*16 + (c&15)], as bf16.
__global__ __launch_bounds__(256, 2) void gx_gemm(
    const int* __restrict__ x, const float* __restrict__ emb,
    const float* __restrict__ W_ih, const float* __restrict__ b_ih,
    const float* __restrict__ b_hh, unsigned short* __restrict__ gx)
{
  __shared__ float As[64][40];   // pad to 40 floats (160B, 16B-aligned rows)
  __shared__ float Bs[64][40];
  __shared__ int   xs[64];

  const int tid = threadIdx.x;
  const int bm = blockIdx.x;   // t tile
  const int bn = blockIdx.y;   // c tile

  if (tid < 64) xs[tid] = x[bm * 64 + tid];
  __syncthreads();

  float acc[4][4] = {};
  const int r0 = (tid >> 4) * 4;  // 4 consecutive rows (t)
  const int c0 = tid & 15;        // 4 cols strided by 16

  for (int kc = 0; kc < 512; kc += 32) {
#pragma unroll
    for (int h = 0; h < 2; ++h) {
      const int v = tid + h * 256;
      const int row = v >> 3, k4 = v & 7;
      const float4 av = *(const float4*)(emb + (size_t)xs[row] * 512 + kc + k4 * 4);
      As[row][k4 * 4 + 0] = av.x; As[row][k4 * 4 + 1] = av.y;
      As[row][k4 * 4 + 2] = av.z; As[row][k4 * 4 + 3] = av.w;
      const float4 bv = *(const float4*)(W_ih + (size_t)(bn * 64 + row) * 512 + kc + k4 * 4);
      Bs[row][k4 * 4 + 0] = bv.x; Bs[row][k4 * 4 + 1] = bv.y;
      Bs[row][k4 * 4 + 2] = bv.z; Bs[row][k4 * 4 + 3] = bv.w;
    }
    __syncthreads();
#pragma unroll
    for (int k4 = 0; k4 < 8; ++k4) {
      float4 a[4], b[4];
#pragma unroll
      for (int i = 0; i < 4; ++i) a[i] = *(const float4*)&As[r0 + i][k4 * 4];
#pragma unroll
      for (int j = 0; j < 4; ++j) b[j] = *(const float4*)&Bs[c0 + j * 16][k4 * 4];
#pragma unroll
      for (int i = 0; i < 4; ++i)
#pragma unroll
        for (int j = 0; j < 4; ++j) {
          acc[i][j] = __builtin_fmaf(a[i].x, b[j].x, acc[i][j]);
          acc[i][j] = __builtin_fmaf(a[i].y, b[j].y, acc[i][j]);
          acc[i][j] = __builtin_fmaf(a[i].z, b[j].z, acc[i][j]);
          acc[i][j] = __builtin_fmaf(a[i].w, b[j].w, acc[i][j]);
        }
    }
    __syncthreads();
  }

#pragma unroll
  for (int j = 0; j < 4; ++j) {
    const int c = bn * 64 + c0 + j * 16;
    const float bias = b_ih[c] + b_hh[c];
    const int rem = c & 511;
    const size_t dstc = (size_t)(rem >> 4) * 64 + (size_t)(c >> 9) * 16 + (c & 15);
#pragma unroll
    for (int i = 0; i < 4; ++i) {
      const size_t t = (size_t)bm * 64 + r0 + i;
      gx[t * 2048 + dstc] = f2bf(acc[i][j] + bias);
    }
  }
}

// ---------------- Phase 2: persistent recurrence ----------------
__global__ __launch_bounds__(256, 1) void lstm_rec(
    const float* __restrict__ W_hh, const unsigned short* __restrict__ gx,
    const float* __restrict__ W1, const float* __restrict__ b1,
    const float* __restrict__ W2, const float* __restrict__ b2,
    float* __restrict__ out,
    unsigned long long* __restrict__ h_glob,  // [2][256] ulong (2 packed f32)
    unsigned int* __restrict__ cnt)
{
  const int w = blockIdx.x;
  const int tid = threadIdx.x;
  const int s = tid & 31;    // K-slice: k in [s*16, s*16+16)
  const int rg = tid >> 5;   // row group: rows rg*8 .. rg*8+7 (r = gate*16+jl)

  // W_hh slice resident in VGPRs: 8 rows x 16 k = 128 floats/thread.
  float wreg[8][16];
#pragma unroll
  for (int q = 0; q < 8; ++q) {
    const int r = rg * 8 + q;
    const int gate = r >> 4;
    const int jl = r & 15;
    const float* src = W_hh + ((size_t)(gate * 512 + w * HW + jl)) * 512 + s * 16;
#pragma unroll
    for (int i4 = 0; i4 < 4; ++i4) {
      const float4 v = *(const float4*)(src + i4 * 4);
      wreg[q][i4 * 4 + 0] = v.x; wreg[q][i4 * 4 + 1] = v.y;
      wreg[q][i4 * 4 + 2] = v.z; wreg[q][i4 * 4 + 3] = v.w;
    }
  }

  __shared__ float dot_lds[64];
  __shared__ float hstage[HW];
  __shared__ unsigned short gx_lds[2][64];

  float c_reg = 0.f;       // cell state (valid for tid < HW)
  float h_reg[16];
#pragma unroll
  for (int i = 0; i < 16; ++i) h_reg[i] = 0.f;

  // gx prefetch pipeline (distance 2)
  unsigned short gpre = 0;
  if (tid < 64) {
    gx_lds[0][tid] = gx[(size_t)0 * 2048 + w * 64 + tid];
    gpre = gx[(size_t)1 * 2048 + w * 64 + tid];
  }
  __syncthreads();

  for (int t = 0; t < S_LEN; ++t) {
    // prefetch gx[t+2]; commit gx[t+1] to LDS
    unsigned short gnew = 0;
    if (tid < 64 && t + 2 < S_LEN)
      gnew = gx[(size_t)(t + 2) * 2048 + w * 64 + tid];
    if (tid < 64 && t + 1 < S_LEN)
      gx_lds[(t + 1) & 1][tid] = gpre;
    gpre = gnew;

    // partial dots: acc[q] = sum_i wreg[q][i] * h[s*16+i]
    float acc[8];
#pragma unroll
    for (int q = 0; q < 8; ++q) {
      float a = 0.f;
#pragma unroll
      for (int i = 0; i < 16; ++i) a = __builtin_fmaf(wreg[q][i], h_reg[i], a);
      acc[q] = a;
    }
    // butterfly reduce over the 32 K-slices (stays within 32-lane half)
#pragma unroll
    for (int q = 0; q < 8; ++q) {
      float a = acc[q];
      a += __shfl_xor(a, 1);
      a += __shfl_xor(a, 2);
      a += __shfl_xor(a, 4);
      a += __shfl_xor(a, 8);
      a += __shfl_xor(a, 16);
      acc[q] = a;
    }
    if (s == 0) {
#pragma unroll
      for (int q = 0; q < 8; ++q) dot_lds[rg * 8 + q] = acc[q];
    }
    __syncthreads();  // A

    if (tid < HW) {
      const int jl = tid;
      const int tb = t & 1;
      const float pi = dot_lds[jl]      + bf2f(gx_lds[tb][jl]);
      const float pf = dot_lds[16 + jl] + bf2f(gx_lds[tb][16 + jl]);
      const float pg = dot_lds[32 + jl] + bf2f(gx_lds[tb][32 + jl]);
      const float po = dot_lds[48 + jl] + bf2f(gx_lds[tb][48 + jl]);
      const float ig = fsig(pi), fg = fsig(pf), gg = ftanh(pg), og = fsig(po);
      c_reg = fg * c_reg + ig * gg;
      hstage[jl] = og * ftanh(c_reg);
    }
    __syncthreads();  // B

    if (tid == 0) {
      const int buf = (t + 1) & 1;
#pragma unroll
      for (int p = 0; p < 8; ++p) {
        union { float f[2]; unsigned long long u; } pk;
        pk.f[0] = hstage[p * 2]; pk.f[1] = hstage[p * 2 + 1];
        __hip_atomic_store(&h_glob[buf * 256 + w * 8 + p], pk.u,
                           __ATOMIC_RELAXED, __HIP_MEMORY_SCOPE_AGENT);
      }
      __threadfence();  // publish h slice before arrival
      __hip_atomic_fetch_add(cnt, 1u, __ATOMIC_RELEASE, __HIP_MEMORY_SCOPE_AGENT);
      const unsigned target = (unsigned)NWG * (unsigned)(t + 1);
      while (__hip_atomic_load(cnt, __ATOMIC_ACQUIRE, __HIP_MEMORY_SCOPE_AGENT) < target) { }
    }
    __syncthreads();  // C

    if (t + 1 < S_LEN) {
      const int buf = (t + 1) & 1;
#pragma unroll
      for (int p = 0; p < 8; ++p) {
        union { unsigned long long u; float f[2]; } pk;
        pk.u = __hip_atomic_load(&h_glob[buf * 256 + s * 8 + p],
                                 __ATOMIC_RELAXED, __HIP_MEMORY_SCOPE_AGENT);
        h_reg[p * 2] = pk.f[0]; h_reg[p * 2 + 1] = pk.f[1];
      }
    }
  }

  // ---------------- Phase 3: head (wg 0) ----------------
  if (w == 0) {
    __shared__ float hl[512];
    __shared__ float zl[128];
    {
      union { unsigned long long u; float f[2]; } pk;   // final h is in buf 0 (S even)
      pk.u = __hip_atomic_load(&h_glob[tid], __ATOMIC_RELAXED, __HIP_MEMORY_SCOPE_AGENT);
      hl[tid * 2] = pk.f[0]; hl[tid * 2 + 1] = pk.f[1];
    }
    __syncthreads();
    const int j = tid >> 1, half = tid & 1;
    float sum = 0.f;
    const float4* w1v = (const float4*)(W1 + (size_t)j * 512 + half * 256);
#pragma unroll 8
    for (int k4 = 0; k4 < 64; ++k4) {
      const float4 v = w1v[k4];
      const int kb = half * 256 + k4 * 4;
      sum = __builtin_fmaf(v.x, hl[kb + 0], sum);
      sum = __builtin_fmaf(v.y, hl[kb + 1], sum);
      sum = __builtin_fmaf(v.z, hl[kb + 2], sum);
      sum = __builtin_fmaf(v.w, hl[kb + 3], sum);
    }
    sum += __shfl_xor(sum, 1);
    if (half == 0) zl[j] = fsig(sum + b1[j]);
    __syncthreads();
    if (tid < 9) {
      float o = b2[tid];
      const float* w2r = W2 + tid * 128;
#pragma unroll 16
      for (int k = 0; k < 128; ++k) o = __builtin_fmaf(w2r[k], zl[k], o);
      out[tid] = fsig(o);
    }
  }
}

extern "C" void kernel_launch(void* const* d_in, const int* in_sizes, int n_in,
                              void* d_out, int out_size, void* d_ws, size_t ws_size,
                              hipStream_t stream) {
  const int*   x     = (const int*)d_in[0];
  const float* emb   = (const float*)d_in[1];
  const float* W_ih  = (const float*)d_in[2];
  const float* W_hh  = (const float*)d_in[3];
  const float* b_ih  = (const float*)d_in[4];
  const float* b_hh  = (const float*)d_in[5];
  const float* W1    = (const float*)d_in[6];
  const float* b1    = (const float*)d_in[7];
  const float* W2    = (const float*)d_in[8];
  const float* b2    = (const float*)d_in[9];
  float* out = (float*)d_out;

  const size_t gx_bytes = (size_t)S_LEN * 2048 * sizeof(unsigned short); // 64 MB
  const size_t h_off    = gx_bytes;
  const size_t cnt_off  = h_off + 4096;
  if (ws_size < cnt_off + 64) return;  // workspace too small: fail visibly

  unsigned short*     gx     = (unsigned short*)d_ws;
  unsigned long long* h_glob = (unsigned long long*)((char*)d_ws + h_off);
  unsigned int*       cnt    = (unsigned int*)((char*)d_ws + cnt_off);

  hipMemsetAsync(cnt, 0, sizeof(unsigned int), stream);

  dim3 g1(S_LEN / 64, 2048 / 64);
  gx_gemm<<<g1, 256, 0, stream>>>(x, emb, W_ih, b_ih, b_hh, gx);
  lstm_rec<<<NWG, 256, 0, stream>>>(W_hh, gx, W1, b1, W2, b2, out, h_glob, cnt);
}

// Round 3
// 61714.966 us; speedup vs baseline: 1.0636x; 1.0636x over previous
//
#include <hip/hip_runtime.h>
#include <hip/hip_bf16.h>

// LSTM: V=50000, E=512, H=512, S=16384, batch=1.
// Phase 1: gx[t][c] = emb[x[t]] . W_ih[c] + (b_ih[c]+b_hh[c])  (fp32 GEMM, bf16 store, permuted cols)
// Phase 2: persistent 16-wg kernel (512 thr), flag-array barrier per timestep, W_hh slice in VGPRs.
// Phase 3 (inside phase 2, wg 0): sigmoid(h W1^T+b1) -> sigmoid(. W2^T+b2) -> out[9].

#define S_LEN 16384
#define HID   512
#define NWG   16
#define HW    32      // hidden units per wg
#define NTHR  512

static __device__ __forceinline__ float bf2f(unsigned short u) {
  union { unsigned int i; float f; } v; v.i = ((unsigned int)u) << 16; return v.f;
}
static __device__ __forceinline__ unsigned short f2bf(float f) {
  union { float f; unsigned int i; } v; v.f = f;
  unsigned int r = v.i + 0x7fffu + ((v.i >> 16) & 1u);
  return (unsigned short)(r >> 16);
}
static __device__ __forceinline__ float fsig(float x) { return 1.f / (1.f + __expf(-x)); }
static __device__ __forceinline__ float ftanh(float x) { return 2.f / (1.f + __expf(-2.f * x)) - 1.f; }

// ---------------- Phase 1: gx GEMM ----------------
// C[t][c] over t-tile 64 x c-tile 64, K=512 in chunks of 32. fp32 VALU.
// Store permuted for NWG=16/HW=32: gx[t][ w*128 + gate*32 + jl ], w=(c&511)>>5, gate=c>>9, jl=c&31.
__global__ __launch_bounds__(256, 2) void gx_gemm(
    const int* __restrict__ x, const float* __restrict__ emb,
    const float* __restrict__ W_ih, const float* __restrict__ b_ih,
    const float* __restrict__ b_hh, unsigned short* __restrict__ gx)
{
  __shared__ float As[64][40];
  __shared__ float Bs[64][40];
  __shared__ int   xs[64];

  const int tid = threadIdx.x;
  const int bm = blockIdx.x;   // t tile
  const int bn = blockIdx.y;   // c tile

  if (tid < 64) xs[tid] = x[bm * 64 + tid];
  __syncthreads();

  float acc[4][4] = {};
  const int r0 = (tid >> 4) * 4;
  const int c0 = tid & 15;

  for (int kc = 0; kc < 512; kc += 32) {
#pragma unroll
    for (int h = 0; h < 2; ++h) {
      const int v = tid + h * 256;
      const int row = v >> 3, k4 = v & 7;
      const float4 av = *(const float4*)(emb + (size_t)xs[row] * 512 + kc + k4 * 4);
      As[row][k4 * 4 + 0] = av.x; As[row][k4 * 4 + 1] = av.y;
      As[row][k4 * 4 + 2] = av.z; As[row][k4 * 4 + 3] = av.w;
      const float4 bv = *(const float4*)(W_ih + (size_t)(bn * 64 + row) * 512 + kc + k4 * 4);
      Bs[row][k4 * 4 + 0] = bv.x; Bs[row][k4 * 4 + 1] = bv.y;
      Bs[row][k4 * 4 + 2] = bv.z; Bs[row][k4 * 4 + 3] = bv.w;
    }
    __syncthreads();
#pragma unroll
    for (int k4 = 0; k4 < 8; ++k4) {
      float4 a[4], b[4];
#pragma unroll
      for (int i = 0; i < 4; ++i) a[i] = *(const float4*)&As[r0 + i][k4 * 4];
#pragma unroll
      for (int j = 0; j < 4; ++j) b[j] = *(const float4*)&Bs[c0 + j * 16][k4 * 4];
#pragma unroll
      for (int i = 0; i < 4; ++i)
#pragma unroll
        for (int j = 0; j < 4; ++j) {
          acc[i][j] = __builtin_fmaf(a[i].x, b[j].x, acc[i][j]);
          acc[i][j] = __builtin_fmaf(a[i].y, b[j].y, acc[i][j]);
          acc[i][j] = __builtin_fmaf(a[i].z, b[j].z, acc[i][j]);
          acc[i][j] = __builtin_fmaf(a[i].w, b[j].w, acc[i][j]);
        }
    }
    __syncthreads();
  }

#pragma unroll
  for (int j = 0; j < 4; ++j) {
    const int c = bn * 64 + c0 + j * 16;
    const float bias = b_ih[c] + b_hh[c];
    const size_t dstc = (size_t)((c & 511) >> 5) * 128 + (size_t)(c >> 9) * 32 + (c & 31);
#pragma unroll
    for (int i = 0; i < 4; ++i) {
      const size_t t = (size_t)bm * 64 + r0 + i;
      gx[t * 2048 + dstc] = f2bf(acc[i][j] + bias);
    }
  }
}

// ---------------- Phase 2: persistent recurrence ----------------
__global__ __launch_bounds__(NTHR, 2) void lstm_rec(
    const float* __restrict__ W_hh, const unsigned short* __restrict__ gx,
    const float* __restrict__ W1, const float* __restrict__ b1,
    const float* __restrict__ W2, const float* __restrict__ b2,
    float* __restrict__ out,
    unsigned long long* __restrict__ h_glob,  // [2][256] ulong (2 packed f32)
    unsigned int* __restrict__ flags)          // [NWG] arrival flags, one line
{
  const int w = blockIdx.x;
  const int tid = threadIdx.x;
  const int s = tid & 31;    // K-slice: k in [s*16, s*16+16)
  const int rg = tid >> 5;   // row group: rows rg*8 .. rg*8+7 of the wg's 128 gate rows

  // W_hh slice resident in VGPRs: 8 rows x 16 k = 128 floats/thread.
  // wg w owns hidden units [w*32, w*32+32); gate rows: gate*512 + w*32 + jl.
  float wreg[8][16];
#pragma unroll
  for (int q = 0; q < 8; ++q) {
    const int r = rg * 8 + q;          // 0..127
    const int gate = r >> 5;
    const int jl = r & 31;
    const float* src = W_hh + ((size_t)(gate * 512 + w * HW + jl)) * 512 + s * 16;
#pragma unroll
    for (int i4 = 0; i4 < 4; ++i4) {
      const float4 v = *(const float4*)(src + i4 * 4);
      wreg[q][i4 * 4 + 0] = v.x; wreg[q][i4 * 4 + 1] = v.y;
      wreg[q][i4 * 4 + 2] = v.z; wreg[q][i4 * 4 + 3] = v.w;
    }
  }

  __shared__ float dot_lds[128];
  __shared__ unsigned short gx_lds[2][128];

  float c_reg = 0.f;       // cell state (lanes jl<32 of wave 0)
  float h_reg[16];
#pragma unroll
  for (int i = 0; i < 16; ++i) h_reg[i] = 0.f;

  // gx prefetch pipeline (distance 2)
  unsigned short gpre = 0;
  if (tid < 128) {
    gx_lds[0][tid] = gx[(size_t)0 * 2048 + w * 128 + tid];
    gpre = gx[(size_t)1 * 2048 + w * 128 + tid];
  }
  __syncthreads();

  for (int t = 0; t < S_LEN; ++t) {
    // prefetch gx[t+2]; commit gx[t+1] to LDS
    unsigned short gnew = 0;
    if (tid < 128 && t + 2 < S_LEN)
      gnew = gx[(size_t)(t + 2) * 2048 + w * 128 + tid];
    if (tid < 128 && t + 1 < S_LEN)
      gx_lds[(t + 1) & 1][tid] = gpre;
    gpre = gnew;

    // partial dots: acc[q] = sum_i wreg[q][i] * h[s*16+i]
    float acc[8];
#pragma unroll
    for (int q = 0; q < 8; ++q) {
      float a = 0.f;
#pragma unroll
      for (int i = 0; i < 16; ++i) a = __builtin_fmaf(wreg[q][i], h_reg[i], a);
      acc[q] = a;
    }
#pragma unroll
    for (int q = 0; q < 8; ++q) {
      float a = acc[q];
      a += __shfl_xor(a, 1);
      a += __shfl_xor(a, 2);
      a += __shfl_xor(a, 4);
      a += __shfl_xor(a, 8);
      a += __shfl_xor(a, 16);
      acc[q] = a;
    }
    if (s == 0) {
#pragma unroll
      for (int q = 0; q < 8; ++q) dot_lds[rg * 8 + q] = acc[q];
    }
    __syncthreads();  // A — dots visible to wave 0

    // ---- wave 0: gates, publish, flag, spin (other waves wait at B) ----
    if (tid < 64) {
      float hv = 0.f;
      const int tb = t & 1;
      if (tid < 32) {
        const int jl = tid;
        const float pi = dot_lds[jl]      + bf2f(gx_lds[tb][jl]);
        const float pf = dot_lds[32 + jl] + bf2f(gx_lds[tb][32 + jl]);
        const float pg = dot_lds[64 + jl] + bf2f(gx_lds[tb][64 + jl]);
        const float po = dot_lds[96 + jl] + bf2f(gx_lds[tb][96 + jl]);
        const float ig = fsig(pi), fg = fsig(pf), gg = ftanh(pg), og = fsig(po);
        c_reg = fg * c_reg + ig * gg;
        hv = og * ftanh(c_reg);
      }
      // pack pairs: lane p<16 stores {h[2p], h[2p+1]}
      const float v0 = __shfl(hv, (tid & 15) * 2);
      const float v1 = __shfl(hv, (tid & 15) * 2 + 1);
      const int buf = (t + 1) & 1;
      if (tid < 16) {
        union { float f[2]; unsigned long long u; } pk;
        pk.f[0] = v0; pk.f[1] = v1;
        __hip_atomic_store(&h_glob[buf * 256 + w * 16 + tid], pk.u,
                           __ATOMIC_RELAXED, __HIP_MEMORY_SCOPE_AGENT);
      }
      __builtin_amdgcn_fence(__ATOMIC_RELEASE, "agent"); // drain slice stores
      if (tid == 0)
        __hip_atomic_store(&flags[w], (unsigned)(t + 1),
                           __ATOMIC_RELAXED, __HIP_MEMORY_SCOPE_AGENT);
      // read-only spin: lane l polls flags[l&15]; no RMW, single line
      const unsigned tgt = (unsigned)(t + 1);
      for (;;) {
        const unsigned fv = __hip_atomic_load(&flags[tid & 15],
                             __ATOMIC_RELAXED, __HIP_MEMORY_SCOPE_AGENT);
        if (__all(fv >= tgt)) break;
        __builtin_amdgcn_s_sleep(1);
      }
      __builtin_amdgcn_fence(__ATOMIC_ACQUIRE, "agent");
    }
    __syncthreads();  // B — h_{t+1} globally visible

    if (t + 1 < S_LEN) {
      const int buf = (t + 1) & 1;
#pragma unroll
      for (int p = 0; p < 8; ++p) {
        union { unsigned long long u; float f[2]; } pk;
        pk.u = __hip_atomic_load(&h_glob[buf * 256 + s * 8 + p],
                                 __ATOMIC_RELAXED, __HIP_MEMORY_SCOPE_AGENT);
        h_reg[p * 2] = pk.f[0]; h_reg[p * 2 + 1] = pk.f[1];
      }
    }
  }

  // ---------------- Phase 3: head (wg 0) ----------------
  if (w == 0) {
    __shared__ float hl[512];
    __shared__ float zl[128];
    if (tid < 256) {
      union { unsigned long long u; float f[2]; } pk;   // final h in buf 0 (S even)
      pk.u = __hip_atomic_load(&h_glob[tid], __ATOMIC_RELAXED, __HIP_MEMORY_SCOPE_AGENT);
      hl[tid * 2] = pk.f[0]; hl[tid * 2 + 1] = pk.f[1];
    }
    __syncthreads();
    // W1: 128 rows x 512 K; 4 threads per row
    const int j = tid >> 2, q = tid & 3;
    float sum = 0.f;
    const float4* w1v = (const float4*)(W1 + (size_t)j * 512 + q * 128);
#pragma unroll 8
    for (int k4 = 0; k4 < 32; ++k4) {
      const float4 v = w1v[k4];
      const int kb = q * 128 + k4 * 4;
      sum = __builtin_fmaf(v.x, hl[kb + 0], sum);
      sum = __builtin_fmaf(v.y, hl[kb + 1], sum);
      sum = __builtin_fmaf(v.z, hl[kb + 2], sum);
      sum = __builtin_fmaf(v.w, hl[kb + 3], sum);
    }
    sum += __shfl_xor(sum, 1);
    sum += __shfl_xor(sum, 2);
    if (q == 0) zl[j] = fsig(sum + b1[j]);
    __syncthreads();
    if (tid < 9) {
      float o = b2[tid];
      const float* w2r = W2 + tid * 128;
#pragma unroll 16
      for (int k = 0; k < 128; ++k) o = __builtin_fmaf(w2r[k], zl[k], o);
      out[tid] = fsig(o);
    }
  }
}

extern "C" void kernel_launch(void* const* d_in, const int* in_sizes, int n_in,
                              void* d_out, int out_size, void* d_ws, size_t ws_size,
                              hipStream_t stream) {
  const int*   x     = (const int*)d_in[0];
  const float* emb   = (const float*)d_in[1];
  const float* W_ih  = (const float*)d_in[2];
  const float* W_hh  = (const float*)d_in[3];
  const float* b_ih  = (const float*)d_in[4];
  const float* b_hh  = (const float*)d_in[5];
  const float* W1    = (const float*)d_in[6];
  const float* b1    = (const float*)d_in[7];
  const float* W2    = (const float*)d_in[8];
  const float* b2    = (const float*)d_in[9];
  float* out = (float*)d_out;

  const size_t gx_bytes = (size_t)S_LEN * 2048 * sizeof(unsigned short); // 64 MB
  const size_t h_off    = gx_bytes;
  const size_t flag_off = h_off + 4096;
  if (ws_size < flag_off + 256) return;  // workspace too small: fail visibly

  unsigned short*     gxp    = (unsigned short*)d_ws;
  unsigned long long* h_glob = (unsigned long long*)((char*)d_ws + h_off);
  unsigned int*       flags  = (unsigned int*)((char*)d_ws + flag_off);

  (void)hipMemsetAsync(flags, 0, NWG * sizeof(unsigned int), stream);

  dim3 g1(S_LEN / 64, 2048 / 64);
  gx_gemm<<<g1, 256, 0, stream>>>(x, emb, W_ih, b_ih, b_hh, gxp);
  lstm_rec<<<NWG, NTHR, 0, stream>>>(W_hh, gxp, W1, b1, W2, b2, out, h_glob, flags);
}